// Round 3
// baseline (64.436 us; speedup 1.0000x reference)
//
#include <hip/hip_runtime.h>
#include <math.h>

// IN_C=3, DIM=256, OUT_C=256, N_PIECES=20, BATCH=16, SET_N=128

#if __has_builtin(__builtin_amdgcn_exp2f)
#define EXP2F(x) __builtin_amdgcn_exp2f(x)
#else
#define EXP2F(x) exp2f(x)
#endif

// ---------------------------------------------------------------------------
// Piecewise-linear pool weight, replicating reference indexing exactly.
// ---------------------------------------------------------------------------
__device__ __forceinline__ float pool_weight(const float* __restrict__ pw, int j)
{
    float ratio = (float)j / 127.0f;
    float idx_f = 20.0f * ratio;
    int idx = (int)idx_f;
    float frac = idx_f - (float)idx;
    int idx2 = idx + 1 > 20 ? 20 : idx + 1;
    return (1.0f - frac) * pw[idx] + frac * pw[idx2];
}

// ---------------------------------------------------------------------------
// K1: fused conv1 + conv2 + fspool.
// Grid: 256 blocks = 16 b x 16 channel-groups of 16. Block: 1024 thr = 16 waves.
// Phase 1 (GEMM): s[d][n] = b2[d] + sum_k W2[d,k]*relu(b1[k]+w1[k]·x[b,:,n])
//   tile 16 d x 128 n, K=256 in steps of 16, results straight into LDS.
// Phase 2 (fspool): wave w owns row d0+w; computes B_i, then the 128
//   j-softmaxes (2 j per lane), dots with s and pool weights -> pooled[b][c].
// ---------------------------------------------------------------------------
__global__ __launch_bounds__(1024) void fused_kernel(
    const float* __restrict__ x,  const float* __restrict__ w1,
    const float* __restrict__ b1, const float* __restrict__ W2,
    const float* __restrict__ b2, const float* __restrict__ pool_w,
    float* __restrict__ pooled)
{
    __shared__ float4 xs4[128];      // (x0,x1,x2,-) per n
    __shared__ float4 w1p[256];      // (w1[k,0..2], b1[k])
    __shared__ float  As[16][16];    // As[kk][dl] = W2[d0+dl][k0+kk]
    __shared__ float  Bs[16][128];   // relu(conv1) sub-tile
    __shared__ float2 sbB[16][128];  // (s_i, B_i*log2e) per row

    const float LOG2E = 1.4426950408889634f;
    int tid = threadIdx.x;
    int b   = blockIdx.x >> 4;
    int d0  = (blockIdx.x & 15) << 4;

    // one-time staging of x row and conv1 params
    if (tid < 128) {
        int n = tid;
        xs4[n] = make_float4(x[b*384 + n], x[b*384 + 128 + n],
                             x[b*384 + 256 + n], 0.0f);
    } else if (tid < 384) {
        int k = tid - 128;
        w1p[k] = make_float4(w1[k*3], w1[k*3+1], w1[k*3+2], b1[k]);
    }
    __syncthreads();

    int ty = tid >> 6;           // wave index = d-row 0..15
    int tx = tid & 63;           // lane
    float acc0 = 0.0f, acc1 = 0.0f;

    for (int k0 = 0; k0 < 256; k0 += 16) {
        if (tid < 256) {
            int dl = tid >> 4, kk = tid & 15;
            As[kk][dl] = W2[(d0 + dl)*256 + k0 + kk];
        }
        #pragma unroll
        for (int q = 0; q < 2; q++) {
            int krel = ((tid >> 7) << 1) + q;    // 0..15
            int nl   = tid & 127;
            float4 w  = w1p[k0 + krel];
            float4 xv = xs4[nl];
            float h = fmaf(w.x, xv.x, fmaf(w.y, xv.y, fmaf(w.z, xv.z, w.w)));
            Bs[krel][nl] = fmaxf(h, 0.0f);
        }
        __syncthreads();
        #pragma unroll
        for (int kk = 0; kk < 16; kk++) {
            float a = As[kk][ty];                        // wave-uniform
            float2 bv = *(const float2*)(&Bs[kk][tx*2]);
            acc0 = fmaf(a, bv.x, acc0);
            acc1 = fmaf(a, bv.y, acc1);
        }
        __syncthreads();
    }

    // GEMM epilogue: s values into sbB (row ty written by wave ty only)
    float bias = b2[d0 + ty];
    sbB[ty][tx*2 + 0].x = acc0 + bias;
    sbB[ty][tx*2 + 1].x = acc1 + bias;
    __syncthreads();   // cheap safety; all later accesses are wave-local

    // ---- fspool, wave-local: row r = ty, lane = tx ----
    int w = ty, lane = tx;

    float si0 = sbB[w][lane].x;
    float si1 = sbB[w][lane + 64].x;
    float B0 = 0.0f, B1 = 0.0f;
    #pragma unroll 8
    for (int j = 0; j < 128; j++) {
        float sj = sbB[w][j].x;                          // broadcast
        B0 += fabsf(si0 - sj);
        B1 += fabsf(si1 - sj);
    }
    sbB[w][lane].y      = B0 * LOG2E;
    sbB[w][lane + 64].y = B1 * LOG2E;

    float scal0 = (float)(127 - 2*lane) * LOG2E;
    float scal1 = (float)(127 - 2*(lane + 64)) * LOG2E;
    float m0 = -1e30f, m1 = -1e30f;
    #pragma unroll 8
    for (int i = 0; i < 128; i++) {
        float2 v = sbB[w][i];                            // broadcast b64
        m0 = fmaxf(m0, fmaf(v.x, scal0, -v.y));
        m1 = fmaxf(m1, fmaf(v.x, scal1, -v.y));
    }
    float se0 = 0.0f, sd0 = 0.0f, se1 = 0.0f, sd1 = 0.0f;
    #pragma unroll 4
    for (int i = 0; i < 128; i++) {
        float2 v = sbB[w][i];
        float e0 = EXP2F(fmaf(v.x, scal0, -v.y) - m0);
        float e1 = EXP2F(fmaf(v.x, scal1, -v.y) - m1);
        se0 += e0; sd0 = fmaf(e0, v.x, sd0);
        se1 += e1; sd1 = fmaf(e1, v.x, sd1);
    }
    float xs0 = sd0 / se0;
    float xs1 = sd1 / se1;

    int c = d0 + w;
    const float* pw = pool_w + c * 21;
    float part = xs0 * pool_weight(pw, lane) + xs1 * pool_weight(pw, lane + 64);

    #pragma unroll
    for (int off = 32; off > 0; off >>= 1)
        part += __shfl_xor(part, off);
    if (lane == 0) pooled[b * 256 + c] = part;
}

// ---------------------------------------------------------------------------
// K2: fused MLP tail, 1024 threads, one block per batch row.
// ---------------------------------------------------------------------------
__device__ __forceinline__ void dense1024(
    const float* __restrict__ W, const float* __restrict__ Bv,
    const float* in_lds, float* out_lds, int tid, bool do_relu)
{
    int o = tid >> 2, p = tid & 3;
    const float* wr = W + o * 256 + p * 64;
    const float* ir = in_lds + p * 64;
    float acc = 0.0f;
    #pragma unroll
    for (int k = 0; k < 64; k += 4) {
        float4 wv = *(const float4*)(wr + k);
        float4 iv = *(const float4*)(ir + k);
        acc = fmaf(wv.x, iv.x, acc);
        acc = fmaf(wv.y, iv.y, acc);
        acc = fmaf(wv.z, iv.z, acc);
        acc = fmaf(wv.w, iv.w, acc);
    }
    acc += __shfl_xor(acc, 1);
    acc += __shfl_xor(acc, 2);
    if (p == 0) {
        acc += Bv[o];
        out_lds[o] = do_relu ? fmaxf(acc, 0.0f) : acc;
    }
}

__global__ __launch_bounds__(1024) void tail_kernel(
    const float* __restrict__ pooled,
    const float* __restrict__ W1, const float* __restrict__ B1,
    const float* __restrict__ W2, const float* __restrict__ B2,
    const float* __restrict__ W3, const float* __restrict__ B3,
    const float* __restrict__ W4, const float* __restrict__ B4,
    float* __restrict__ out)
{
    __shared__ float za[256], zb[256];
    int b = blockIdx.x, tid = threadIdx.x;
    if (tid < 256) za[tid] = pooled[b * 256 + tid];
    __syncthreads();
    dense1024(W1, B1, za, zb, tid, true);    // lin1 + relu
    __syncthreads();
    dense1024(W2, B2, zb, za, tid, false);   // lin2
    __syncthreads();
    dense1024(W3, B3, za, zb, tid, true);    // cls1 + relu
    __syncthreads();
    if (tid < 640) {
        int o = tid >> 6, kb = tid & 63;
        float4 wv = *(const float4*)(W4 + o * 256 + kb * 4);
        float4 zv = *(const float4*)(zb + kb * 4);
        float p = fmaf(wv.x, zv.x, fmaf(wv.y, zv.y,
                  fmaf(wv.z, zv.z, wv.w * zv.w)));
        #pragma unroll
        for (int off = 32; off > 0; off >>= 1)
            p += __shfl_xor(p, off);
        if (kb == 0) out[b * 10 + o] = p + B4[o];
    }
}

// ---------------------------------------------------------------------------
extern "C" void kernel_launch(void* const* d_in, const int* in_sizes, int n_in,
                              void* d_out, int out_size, void* d_ws, size_t ws_size,
                              hipStream_t stream)
{
    (void)in_sizes; (void)n_in; (void)out_size; (void)ws_size;
    const float* x       = (const float*)d_in[0];   // (16,3,128)
    const float* conv1_w = (const float*)d_in[1];   // (256,3)
    const float* conv1_b = (const float*)d_in[2];
    const float* conv2_w = (const float*)d_in[3];   // (256,256)
    const float* conv2_b = (const float*)d_in[4];
    const float* pool_w  = (const float*)d_in[5];   // (256,21)
    const float* lin1_w  = (const float*)d_in[6];
    const float* lin1_b  = (const float*)d_in[7];
    const float* lin2_w  = (const float*)d_in[8];
    const float* lin2_b  = (const float*)d_in[9];
    const float* cls1_w  = (const float*)d_in[10];
    const float* cls1_b  = (const float*)d_in[11];
    const float* cls2_w  = (const float*)d_in[12];  // (10,256)
    const float* cls2_b  = (const float*)d_in[13];
    float* out = (float*)d_out;

    float* pooled = (float*)d_ws;        // 4096 floats

    fused_kernel<<<256, 1024, 0, stream>>>(x, conv1_w, conv1_b,
                                           conv2_w, conv2_b, pool_w, pooled);
    tail_kernel<<<16, 1024, 0, stream>>>(pooled,
        lin1_w, lin1_b, lin2_w, lin2_b, cls1_w, cls1_b, cls2_w, cls2_b, out);
}

// Round 4
// 59.685 us; speedup vs baseline: 1.0796x; 1.0796x over previous
//
#include <hip/hip_runtime.h>
#include <math.h>

// IN_C=3, DIM=256, OUT_C=256, N_PIECES=20, BATCH=16, SET_N=128

#if __has_builtin(__builtin_amdgcn_exp2f)
#define EXP2F(x) __builtin_amdgcn_exp2f(x)
#else
#define EXP2F(x) exp2f(x)
#endif

// ---------------------------------------------------------------------------
// K1: fused conv1+conv2. Tile 16 d x 64 bn, grid (32, 16) = 512 blocks.
// H2[b][d][n] = b2[d] + sum_k W2[d,k] * relu(b1[k] + w1[k]·x[b,:,n])
// ---------------------------------------------------------------------------
__global__ __launch_bounds__(256) void conv12_kernel(
    const float* __restrict__ x, const float* __restrict__ w1,
    const float* __restrict__ b1, const float* __restrict__ W2,
    const float* __restrict__ b2, float* __restrict__ H2)
{
    __shared__ float xs[3][64];
    __shared__ float As[16][16];   // As[kk][dl] = W2[d0+dl][k0+kk]
    __shared__ float Bs[16][64];   // relu(conv1) sub-tile

    int tid = threadIdx.x;
    int bx  = blockIdx.x;
    int d0  = blockIdx.y * 16;
    int b   = bx >> 1;
    int n0  = (bx & 1) * 64;

    if (tid < 192) {
        int c = tid >> 6, n = tid & 63;
        xs[c][n] = x[b * 384 + c * 128 + n0 + n];
    }
    __syncthreads();

    int tx = tid & 15, ty = tid >> 4;   // tx: n-quad, ty: d
    float acc[4] = {};

    for (int k0 = 0; k0 < 256; k0 += 16) {
        {
            int dl = tid & 15, kk = tid >> 4;
            As[kk][dl] = W2[(d0 + dl) * 256 + k0 + kk];
        }
        #pragma unroll
        for (int q = 0; q < 4; q++) {
            int idx = q * 256 + tid;
            int krel = idx >> 6, nl = idx & 63;
            int k = k0 + krel;
            float h = fmaf(w1[k * 3 + 0], xs[0][nl],
                      fmaf(w1[k * 3 + 1], xs[1][nl],
                      fmaf(w1[k * 3 + 2], xs[2][nl], b1[k])));
            Bs[krel][nl] = fmaxf(h, 0.0f);
        }
        __syncthreads();
        #pragma unroll
        for (int kk = 0; kk < 16; kk++) {
            float a  = As[kk][ty];
            float4 bv = *(const float4*)(&Bs[kk][tx * 4]);
            acc[0] = fmaf(a, bv.x, acc[0]);
            acc[1] = fmaf(a, bv.y, acc[1]);
            acc[2] = fmaf(a, bv.z, acc[2]);
            acc[3] = fmaf(a, bv.w, acc[3]);
        }
        __syncthreads();
    }

    int d = d0 + ty;
    float bias = b2[d];
    float4 o = make_float4(acc[0] + bias, acc[1] + bias,
                           acc[2] + bias, acc[3] + bias);
    *(float4*)(H2 + b * 32768 + d * 128 + n0 + tx * 4) = o;
}

// ---------------------------------------------------------------------------
// Piecewise-linear pool weight (reference indexing).
// ---------------------------------------------------------------------------
__device__ __forceinline__ float pool_weight(const float* __restrict__ pw, int j)
{
    float ratio = (float)j / 127.0f;
    float idx_f = 20.0f * ratio;
    int idx = (int)idx_f;
    float frac = idx_f - (float)idx;
    int idx2 = idx + 1 > 20 ? 20 : idx + 1;
    return (1.0f - frac) * pw[idx] + frac * pw[idx2];
}

// ---------------------------------------------------------------------------
// K2: FSPool v2. 256 thr = 4 waves = 2 rows x 2 waves. Each lane owns ONE
// j-position (j = half*64 + lane). Grid 2048 -> 8 blocks/CU = 32 waves/CU.
// LDS: ss (s values) + bb (Bsum*log2e), b128 broadcast reads, 4-way split
// accumulator chains.
// ---------------------------------------------------------------------------
__global__ __launch_bounds__(256, 8) void fspool_kernel(
    const float* __restrict__ s_glob,    // [4096][128]
    const float* __restrict__ pool_w,    // [256][21]
    float* __restrict__ pooled)          // [4096]
{
    const float LOG2E = 1.4426950408889634f;
    __shared__ float ss[2][128];
    __shared__ float bb[2][128];
    __shared__ float part[2][2];

    int tid  = threadIdx.x;
    int wave = tid >> 6;        // 0..3
    int rl   = wave >> 1;       // row-local 0..1
    int half = wave & 1;
    int lane = tid & 63;
    int i    = half * 64 + lane;           // this thread's i and j
    int row  = blockIdx.x * 2 + rl;

    float si = s_glob[row * 128 + i];
    ss[rl][i] = si;
    __syncthreads();

    // Bsum_i = sum_j |s_i - s_j|   (4 split accumulators)
    float a0 = 0.f, a1 = 0.f, a2 = 0.f, a3 = 0.f;
    #pragma unroll 4
    for (int j = 0; j < 128; j += 4) {
        float4 sv = *(const float4*)(&ss[rl][j]);
        a0 += fabsf(si - sv.x);
        a1 += fabsf(si - sv.y);
        a2 += fabsf(si - sv.z);
        a3 += fabsf(si - sv.w);
    }
    bb[rl][i] = ((a0 + a1) + (a2 + a3)) * LOG2E;
    __syncthreads();

    // softmax over i' for this thread's j = i (log2 domain)
    float scal = (float)(127 - 2 * i) * LOG2E;
    float m0 = -1e30f, m1 = -1e30f, m2 = -1e30f, m3 = -1e30f;
    #pragma unroll 4
    for (int k = 0; k < 128; k += 4) {
        float4 sv = *(const float4*)(&ss[rl][k]);
        float4 bv = *(const float4*)(&bb[rl][k]);
        m0 = fmaxf(m0, fmaf(sv.x, scal, -bv.x));
        m1 = fmaxf(m1, fmaf(sv.y, scal, -bv.y));
        m2 = fmaxf(m2, fmaf(sv.z, scal, -bv.z));
        m3 = fmaxf(m3, fmaf(sv.w, scal, -bv.w));
    }
    float m = fmaxf(fmaxf(m0, m1), fmaxf(m2, m3));

    float se0 = 0.f, se1 = 0.f, se2 = 0.f, se3 = 0.f;
    float sd0 = 0.f, sd1 = 0.f, sd2 = 0.f, sd3 = 0.f;
    #pragma unroll 4
    for (int k = 0; k < 128; k += 4) {
        float4 sv = *(const float4*)(&ss[rl][k]);
        float4 bv = *(const float4*)(&bb[rl][k]);
        float e0 = EXP2F(fmaf(sv.x, scal, -bv.x) - m);
        float e1 = EXP2F(fmaf(sv.y, scal, -bv.y) - m);
        float e2 = EXP2F(fmaf(sv.z, scal, -bv.z) - m);
        float e3 = EXP2F(fmaf(sv.w, scal, -bv.w) - m);
        se0 += e0; se1 += e1; se2 += e2; se3 += e3;
        sd0 = fmaf(e0, sv.x, sd0);
        sd1 = fmaf(e1, sv.y, sd1);
        sd2 = fmaf(e2, sv.z, sd2);
        sd3 = fmaf(e3, sv.w, sd3);
    }
    float xs = ((sd0 + sd1) + (sd2 + sd3)) / ((se0 + se1) + (se2 + se3));

    int c = row & 255;
    float p = xs * pool_weight(pool_w + c * 21, i);
    #pragma unroll
    for (int off = 32; off > 0; off >>= 1)
        p += __shfl_xor(p, off);
    if (lane == 0) part[rl][half] = p;
    __syncthreads();
    if (tid < 2)
        pooled[blockIdx.x * 2 + tid] = part[tid][0] + part[tid][1];
}

// ---------------------------------------------------------------------------
// K3: fused MLP tail, 1024 threads, one block per batch row.
// ---------------------------------------------------------------------------
__device__ __forceinline__ void dense1024(
    const float* __restrict__ W, const float* __restrict__ Bv,
    const float* in_lds, float* out_lds, int tid, bool do_relu)
{
    int o = tid >> 2, p = tid & 3;
    const float* wr = W + o * 256 + p * 64;
    const float* ir = in_lds + p * 64;
    float acc = 0.0f;
    #pragma unroll
    for (int k = 0; k < 64; k += 4) {
        float4 wv = *(const float4*)(wr + k);
        float4 iv = *(const float4*)(ir + k);
        acc = fmaf(wv.x, iv.x, acc);
        acc = fmaf(wv.y, iv.y, acc);
        acc = fmaf(wv.z, iv.z, acc);
        acc = fmaf(wv.w, iv.w, acc);
    }
    acc += __shfl_xor(acc, 1);
    acc += __shfl_xor(acc, 2);
    if (p == 0) {
        acc += Bv[o];
        out_lds[o] = do_relu ? fmaxf(acc, 0.0f) : acc;
    }
}

__global__ __launch_bounds__(1024) void tail_kernel(
    const float* __restrict__ pooled,
    const float* __restrict__ W1, const float* __restrict__ B1,
    const float* __restrict__ W2, const float* __restrict__ B2,
    const float* __restrict__ W3, const float* __restrict__ B3,
    const float* __restrict__ W4, const float* __restrict__ B4,
    float* __restrict__ out)
{
    __shared__ float za[256], zb[256];
    int b = blockIdx.x, tid = threadIdx.x;
    if (tid < 256) za[tid] = pooled[b * 256 + tid];
    __syncthreads();
    dense1024(W1, B1, za, zb, tid, true);    // lin1 + relu
    __syncthreads();
    dense1024(W2, B2, zb, za, tid, false);   // lin2
    __syncthreads();
    dense1024(W3, B3, za, zb, tid, true);    // cls1 + relu
    __syncthreads();
    if (tid < 640) {
        int o = tid >> 6, kb = tid & 63;
        float4 wv = *(const float4*)(W4 + o * 256 + kb * 4);
        float4 zv = *(const float4*)(zb + kb * 4);
        float p = fmaf(wv.x, zv.x, fmaf(wv.y, zv.y,
                  fmaf(wv.z, zv.z, wv.w * zv.w)));
        #pragma unroll
        for (int off = 32; off > 0; off >>= 1)
            p += __shfl_xor(p, off);
        if (kb == 0) out[b * 10 + o] = p + B4[o];
    }
}

// ---------------------------------------------------------------------------
extern "C" void kernel_launch(void* const* d_in, const int* in_sizes, int n_in,
                              void* d_out, int out_size, void* d_ws, size_t ws_size,
                              hipStream_t stream)
{
    (void)in_sizes; (void)n_in; (void)out_size; (void)ws_size;
    const float* x       = (const float*)d_in[0];   // (16,3,128)
    const float* conv1_w = (const float*)d_in[1];   // (256,3)
    const float* conv1_b = (const float*)d_in[2];
    const float* conv2_w = (const float*)d_in[3];   // (256,256)
    const float* conv2_b = (const float*)d_in[4];
    const float* pool_w  = (const float*)d_in[5];   // (256,21)
    const float* lin1_w  = (const float*)d_in[6];
    const float* lin1_b  = (const float*)d_in[7];
    const float* lin2_w  = (const float*)d_in[8];
    const float* lin2_b  = (const float*)d_in[9];
    const float* cls1_w  = (const float*)d_in[10];
    const float* cls1_b  = (const float*)d_in[11];
    const float* cls2_w  = (const float*)d_in[12];  // (10,256)
    const float* cls2_b  = (const float*)d_in[13];
    float* out = (float*)d_out;

    float* ws     = (float*)d_ws;
    float* H2     = ws;                 // 524288 floats
    float* pooled = ws + 524288;        // 4096 floats

    conv12_kernel<<<dim3(32, 16), 256, 0, stream>>>(x, conv1_w, conv1_b,
                                                    conv2_w, conv2_b, H2);
    fspool_kernel<<<2048, 256, 0, stream>>>(H2, pool_w, pooled);
    tail_kernel<<<16, 1024, 0, stream>>>(pooled,
        lin1_w, lin1_b, lin2_w, lin2_b, cls1_w, cls1_b, cls2_w, cls2_b, out);
}